// Round 11
// baseline (2200.648 us; speedup 1.0000x reference)
//
#include <hip/hip_runtime.h>

#define NI 8
#define NH 64
#define NO 8
#define NB 256
#define NT 2048
#define RING 16

typedef float v2f __attribute__((ext_vector_type(2)));

__device__ __forceinline__ v2f fma2(v2f a, v2f b, v2f c) {
    return __builtin_elementwise_fma(a, b, c);
}

__device__ __forceinline__ float tanh_fast(float s) {
    float e = __expf(2.0f * s);
    return fmaf(-2.0f, __builtin_amdgcn_rcpf(e + 1.0f), 1.0f);
}

__device__ __forceinline__ float rlane(float v, int k) {
    return __int_as_float(__builtin_amdgcn_readlane(__float_as_int(v), k));
}

// ===========================================================================
// MEASUREMENT ROUND. Three isolated probes of the serial-chain components,
// launched before the (unchanged) R10 kernel. Readout: dur_us(total) minus
// rnn_pk2's rocprof row = T_fma + T_rl + T_lds; any probe > ~1047us appears
// in the top-5 table by name. 256 blocks x 1 wave, like one pipeline wave.
// ===========================================================================

// P-FMA: gather-free recurrence. 32 pk_fma (4 acc chains of 8) + tanh.
// The floor for ANY structure that keeps a 64-wide dot on the chain.
__attribute__((amdgpu_waves_per_eu(1, 1)))
__global__ void __launch_bounds__(64) probe_fma(const float* __restrict__ W,
                                                float* __restrict__ ws, int nws) {
    const int lane = threadIdx.x;
    v2f w2[NH / 2];
    #pragma unroll
    for (int k = 0; k < NH / 2; ++k)
        w2[k] = v2f{W[lane * NH + 2 * k], W[lane * NH + 2 * k + 1]};
    float h = 0.001f * (float)lane + 1e-5f * (float)blockIdx.x;
    #pragma unroll 1
    for (int t = 0; t < NT; ++t) {
        const v2f hh = {h, h};
        v2f a0 = {0.f, 0.f}, a1 = {0.f, 0.f}, a2 = {0.f, 0.f}, a3 = {0.f, 0.f};
        #pragma unroll
        for (int k = 0; k < 8; ++k) {
            a0 = fma2(hh, w2[4 * k + 0], a0);
            a1 = fma2(hh, w2[4 * k + 1], a1);
            a2 = fma2(hh, w2[4 * k + 2], a2);
            a3 = fma2(hh, w2[4 * k + 3], a3);
        }
        const v2f sv = (a0 + a1) + (a2 + a3);
        h = tanh_fast(sv.x + sv.y);
    }
    if (ws) ws[(blockIdx.x * 64 + lane) % nws] = h;
}

// P-RL: + readlane gather (R7's A-chain core): 64 v_readlane + 64 scalar fma.
__attribute__((amdgpu_waves_per_eu(1, 1)))
__global__ void __launch_bounds__(64) probe_rl(const float* __restrict__ W,
                                               float* __restrict__ ws, int nws) {
    const int lane = threadIdx.x;
    float w[NH];
    #pragma unroll
    for (int k = 0; k < NH; ++k) w[k] = W[lane * NH + k];
    float h = 0.001f * (float)lane + 1e-5f * (float)blockIdx.x;
    #pragma unroll 1
    for (int t = 0; t < NT; ++t) {
        float c0 = 0.f, c1 = 0.f, c2 = 0.f, c3 = 0.f;
        #pragma unroll
        for (int k = 0; k < NH; k += 8) {
            const float s0 = rlane(h, k + 0), s1 = rlane(h, k + 1);
            const float s2 = rlane(h, k + 2), s3 = rlane(h, k + 3);
            const float s4 = rlane(h, k + 4), s5 = rlane(h, k + 5);
            const float s6 = rlane(h, k + 6), s7 = rlane(h, k + 7);
            c0 = fmaf(s0, w[k + 0], c0); c1 = fmaf(s1, w[k + 1], c1);
            c2 = fmaf(s2, w[k + 2], c2); c3 = fmaf(s3, w[k + 3], c3);
            c0 = fmaf(s4, w[k + 4], c0); c1 = fmaf(s5, w[k + 5], c1);
            c2 = fmaf(s6, w[k + 6], c2); c3 = fmaf(s7, w[k + 7], c3);
        }
        h = tanh_fast((c0 + c1) + (c2 + c3));
    }
    if (ws) ws[(blockIdx.x * 64 + lane) % nws] = h;
}

// P-LDS: + LDS write -> 16x ds_read_b128 broadcast gather (R10's A-chain core).
__attribute__((amdgpu_waves_per_eu(1, 1)))
__global__ void __launch_bounds__(64) probe_lds(const float* __restrict__ W,
                                                float* __restrict__ ws, int nws) {
    const int lane = threadIdx.x;
    __shared__ float hs[NH];
    v2f w2[NH / 2];
    #pragma unroll
    for (int k = 0; k < NH / 2; ++k)
        w2[k] = v2f{W[lane * NH + 2 * k], W[lane * NH + 2 * k + 1]};
    float h = 0.001f * (float)lane + 1e-5f * (float)blockIdx.x;
    #pragma unroll 1
    for (int t = 0; t < NT; ++t) {
        hs[lane] = h;
        const float4* hp = (const float4*)hs;
        v2f a0 = {0.f, 0.f}, a1 = {0.f, 0.f}, a2 = {0.f, 0.f}, a3 = {0.f, 0.f};
        #pragma unroll
        for (int k = 0; k < 16; ++k) {
            const float4 g = hp[k];
            const v2f lo = {g.x, g.y}, hi = {g.z, g.w};
            if (k & 1) { a2 = fma2(lo, w2[2 * k], a2); a3 = fma2(hi, w2[2 * k + 1], a3); }
            else       { a0 = fma2(lo, w2[2 * k], a0); a1 = fma2(hi, w2[2 * k + 1], a1); }
        }
        const v2f sv = (a0 + a1) + (a2 + a3);
        h = tanh_fast(sv.x + sv.y);
    }
    if (ws) ws[(blockIdx.x * 64 + lane) % nws] = h;
}

// ===========================================================================
// rnn_pk2: byte-identical to round 10 (passed, 1047us, VGPR=132).
// ===========================================================================
__attribute__((amdgpu_waves_per_eu(1, 1)))
__global__ void __launch_bounds__(192) rnn_pk2(
    const float* __restrict__ x,
    const float* __restrict__ W_ih0, const float* __restrict__ W_hh0,
    const float* __restrict__ b_ih0, const float* __restrict__ b_hh0,
    const float* __restrict__ W_ih1, const float* __restrict__ W_hh1,
    const float* __restrict__ b_ih1, const float* __restrict__ b_hh1,
    const float* __restrict__ W_fc,  const float* __restrict__ b_fc,
    float* __restrict__ out)
{
    const int b    = blockIdx.x;
    const int tid  = threadIdx.x;
    const int wid  = tid >> 6;
    const int lane = tid & 63;
    const int o    = lane & 7;
    const int kg   = lane >> 3;

    __shared__ float xs[2][64][NI];
    __shared__ float h0r[RING][NH];
    __shared__ float pir[RING][NH];
    __shared__ float h1s[NH];
    __shared__ int   af, bfl, cfl;

    if (tid == 0) { af = -1; bfl = -1; cfl = -1; }

    v2f w2[NH / 2];
    const float* wsrc = (wid == 0) ? (W_hh0 + lane * NH)
                      : (wid == 1) ? (W_ih1 + lane * NH)
                                   : (W_hh1 + lane * NH);
    #pragma unroll
    for (int k = 0; k < NH / 2; ++k) w2[k] = v2f{wsrc[2 * k], wsrc[2 * k + 1]};

    v2f wsm2[4];
    const float* ssrc = (wid == 2) ? (W_fc + o * NH + kg * 8)
                                   : (W_ih0 + lane * NI);
    #pragma unroll
    for (int m = 0; m < 4; ++m) wsm2[m] = v2f{ssrc[2 * m], ssrc[2 * m + 1]};

    #pragma unroll
    for (int k = 0; k < NH / 2; ++k) asm("" : "+v"(w2[k]));
    #pragma unroll
    for (int m = 0; m < 4; ++m) asm("" : "+v"(wsm2[m]));

    const float bias  = (wid == 0) ? (b_ih0[lane] + b_hh0[lane])
                      : (wid == 2) ? (b_ih1[lane] + b_hh1[lane]) : 0.0f;
    const float bias2 = (wid == 2) ? b_fc[o] : 0.0f;

    __syncthreads();

    volatile int* vaf = &af;
    volatile int* vbf = &bfl;
    volatile int* vcf = &cfl;

    const float*  xb   = x   + (size_t)b * NT * NI;
    float*        outb = out + (size_t)b * NT * NO;
    const size_t  hid  = (size_t)NB * NT * NO;

    if (wid == 0) {
        h0r[RING - 1][lane] = 0.0f;
        {
            float4 q0 = *(const float4*)(xb + (size_t)lane * NI);
            float4 q1 = *(const float4*)(xb + (size_t)lane * NI + 4);
            *(float4*)(&xs[0][lane][0]) = q0;
            *(float4*)(&xs[0][lane][4]) = q1;
        }
        float4 xn0 = {0, 0, 0, 0}, xn1 = {0, 0, 0, 0};
        float h0n = 0.0f;

        for (int t = 0; t < NT; ++t) {
            const int j = t & 63;
            if (j == 0) {
                const int c = (t >> 6) + 1;
                if (c < NT / 64) {
                    xn0 = *(const float4*)(xb + (size_t)(c * 64 + lane) * NI);
                    xn1 = *(const float4*)(xb + (size_t)(c * 64 + lane) * NI + 4);
                }
            }
            if ((t & 7) == 0) {
                while (*vbf < t - 9) __builtin_amdgcn_s_sleep(1);
                asm volatile("" ::: "memory");
            }

            const float4* hp = (const float4*)(&h0r[(t - 1) & (RING - 1)][0]);
            const float4* xp = (const float4*)(&xs[(t >> 6) & 1][j][0]);
            const float4 xg0 = xp[0], xg1 = xp[1];

            v2f a0 = {bias, 0.f}, a1 = {0.f, 0.f}, a2 = {0.f, 0.f}, a3 = {0.f, 0.f};
            #pragma unroll
            for (int k = 0; k < 16; ++k) {
                const float4 g = hp[k];
                const v2f lo = {g.x, g.y}, hi = {g.z, g.w};
                if (k & 1) { a2 = fma2(lo, w2[2 * k], a2); a3 = fma2(hi, w2[2 * k + 1], a3); }
                else       { a0 = fma2(lo, w2[2 * k], a0); a1 = fma2(hi, w2[2 * k + 1], a1); }
            }
            a0 = fma2(v2f{xg0.x, xg0.y}, wsm2[0], a0);
            a1 = fma2(v2f{xg0.z, xg0.w}, wsm2[1], a1);
            a2 = fma2(v2f{xg1.x, xg1.y}, wsm2[2], a2);
            a3 = fma2(v2f{xg1.z, xg1.w}, wsm2[3], a3);
            const v2f sv = (a0 + a1) + (a2 + a3);
            h0n = tanh_fast(sv.x + sv.y);

            h0r[t & (RING - 1)][lane] = h0n;
            if (t & 1) {
                asm volatile("s_waitcnt lgkmcnt(0)" ::: "memory");
                *vaf = t;
            }
            if (j == 48) {
                const int c = (t >> 6) + 1;
                if (c < NT / 64) {
                    *(float4*)(&xs[c & 1][lane][0]) = xn0;
                    *(float4*)(&xs[c & 1][lane][4]) = xn1;
                }
            }
        }
        out[hid + (size_t)b * NH + lane] = h0n;
    } else if (wid == 1) {
        for (int t = 0; t < NT; ++t) {
            if ((t & 3) == 0) {
                const int need = (t + 3 < NT) ? t + 3 : NT - 1;
                while (*vaf < need) __builtin_amdgcn_s_sleep(1);
                asm volatile("" ::: "memory");
            }
            if ((t & 7) == 0) {
                while (*vcf < t - 9) __builtin_amdgcn_s_sleep(1);
                asm volatile("" ::: "memory");
            }
            const float4* hp = (const float4*)(&h0r[t & (RING - 1)][0]);
            v2f a0 = {0.f, 0.f}, a1 = {0.f, 0.f}, a2 = {0.f, 0.f}, a3 = {0.f, 0.f};
            #pragma unroll
            for (int k = 0; k < 16; ++k) {
                const float4 g = hp[k];
                const v2f lo = {g.x, g.y}, hi = {g.z, g.w};
                if (k & 1) { a2 = fma2(lo, w2[2 * k], a2); a3 = fma2(hi, w2[2 * k + 1], a3); }
                else       { a0 = fma2(lo, w2[2 * k], a0); a1 = fma2(hi, w2[2 * k + 1], a1); }
            }
            const v2f sv = (a0 + a1) + (a2 + a3);
            pir[t & (RING - 1)][lane] = sv.x + sv.y;
            if (t & 1) {
                asm volatile("s_waitcnt lgkmcnt(0)" ::: "memory");
                *vbf = t;
            }
        }
    } else {
        h1s[lane] = 0.0f;
        float h1n = 0.0f;

        for (int t = 0; t < NT; ++t) {
            if ((t & 3) == 0) {
                const int need = (t + 3 < NT) ? t + 3 : NT - 1;
                while (*vbf < need) __builtin_amdgcn_s_sleep(1);
                asm volatile("" ::: "memory");
            }
            const float pv = pir[t & (RING - 1)][lane];

            const float4* hp = (const float4*)(&h1s[0]);
            v2f a0 = {bias, 0.f}, a1 = {0.f, 0.f}, a2 = {0.f, 0.f}, a3 = {0.f, 0.f};
            #pragma unroll
            for (int k = 0; k < 16; ++k) {
                const float4 g = hp[k];
                const v2f lo = {g.x, g.y}, hi = {g.z, g.w};
                if (k & 1) { a2 = fma2(lo, w2[2 * k], a2); a3 = fma2(hi, w2[2 * k + 1], a3); }
                else       { a0 = fma2(lo, w2[2 * k], a0); a1 = fma2(hi, w2[2 * k + 1], a1); }
            }
            const v2f sv = (a0 + a1) + (a2 + a3);
            h1n = tanh_fast(sv.x + sv.y + pv);

            h1s[lane] = h1n;
            const float4 u0 = *(const float4*)(&h1s[kg * 8]);
            const float4 u1 = *(const float4*)(&h1s[kg * 8 + 4]);
            v2f f0 = fma2(v2f{u0.x, u0.y}, wsm2[0], v2f{0.f, 0.f});
            v2f f1 = fma2(v2f{u0.z, u0.w}, wsm2[1], v2f{0.f, 0.f});
            f0 = fma2(v2f{u1.x, u1.y}, wsm2[2], f0);
            f1 = fma2(v2f{u1.z, u1.w}, wsm2[3], f1);
            const v2f fv = f0 + f1;
            float p = fv.x + fv.y;
            p += __shfl_xor(p, 8);
            p += __shfl_xor(p, 16);
            p += __shfl_xor(p, 32);
            if (lane < NO) outb[(size_t)t * NO + o] = p + bias2;

            if ((t & 3) == 3) {
                asm volatile("s_waitcnt lgkmcnt(0)" ::: "memory");
                *vcf = t;
            }
        }
        out[hid + (size_t)NB * NH + (size_t)b * NH + lane] = h1n;
    }
}

extern "C" void kernel_launch(void* const* d_in, const int* in_sizes, int n_in,
                              void* d_out, int out_size, void* d_ws, size_t ws_size,
                              hipStream_t stream) {
    const float* x     = (const float*)d_in[0];
    const float* W_ih0 = (const float*)d_in[1];
    const float* W_hh0 = (const float*)d_in[2];
    const float* b_ih0 = (const float*)d_in[3];
    const float* b_hh0 = (const float*)d_in[4];
    const float* W_ih1 = (const float*)d_in[5];
    const float* W_hh1 = (const float*)d_in[6];
    const float* b_ih1 = (const float*)d_in[7];
    const float* b_hh1 = (const float*)d_in[8];
    const float* W_fc  = (const float*)d_in[9];
    const float* b_fc  = (const float*)d_in[10];

    // ---- measurement probes (durations read via dur_us - rnn rocprof row) ----
    float* wsf = (ws_size >= 4096) ? (float*)d_ws : nullptr;
    const int nws = wsf ? (int)(ws_size / sizeof(float)) : 1;
    probe_fma<<<dim3(NB), dim3(64), 0, stream>>>(W_hh0, wsf, nws);
    probe_rl <<<dim3(NB), dim3(64), 0, stream>>>(W_hh0, wsf, nws);
    probe_lds<<<dim3(NB), dim3(64), 0, stream>>>(W_hh0, wsf, nws);

    // ---- the real kernel (unchanged R10) ----
    rnn_pk2<<<dim3(NB), dim3(192), 0, stream>>>(
        x, W_ih0, W_hh0, b_ih0, b_hh0,
        W_ih1, W_hh1, b_ih1, b_hh1, W_fc, b_fc,
        (float*)d_out);
}

// Round 12
// 814.741 us; speedup vs baseline: 2.7010x; 2.7010x over previous
//
#include <hip/hip_runtime.h>

#define NI 8
#define NH 64
#define NO 8
#define NB 256
#define NT 2048

typedef float v2f __attribute__((ext_vector_type(2)));

__device__ __forceinline__ v2f fma2(v2f a, v2f b, v2f c) {
    return __builtin_elementwise_fma(a, b, c);
}

// tanh(s) = 1 - 2/(exp(2s)+1); safe at +-inf
__device__ __forceinline__ float tanh_fast(float s) {
    float e = __expf(2.0f * s);
    return fmaf(-2.0f, __builtin_amdgcn_rcpf(e + 1.0f), 1.0f);
}

// broadcast lane k's value to all lanes (VALU pipe, no LDS)
__device__ __forceinline__ float rlane(float v, int k) {
    return __int_as_float(__builtin_amdgcn_readlane(__float_as_int(v), k));
}

// 4 waves (one per SIMD), one block per batch element, zero barriers.
// R11 probes: isolated chains avg ~385us vs full kernel 1045 -> the gap is
// shared-resource + coupling, prime suspect the CU-shared DS pipe (~58 DS
// ops/step in R10) and s_sleep(64cyc-quanta) multi-hop polling. This round:
//   A: h0 chain, readlane self-gather (VALU only, 2 DS ops/step)
//   B: pi[t]=Wih1@h0[t], the only LDS-heavy wave (16 b128 bcast, 17 DS)
//   C: h1 chain, readlane self-gather (3 DS)
//   D: u[t]=Wih0@x[t]+bias0 producer (x-dot off A's chain) + FC + store
// All waits: gran-1 busy-spin (each wave alone on its SIMD -> spinning free).
__attribute__((amdgpu_waves_per_eu(1, 1)))
__global__ void __launch_bounds__(256) rnn_quad(
    const float* __restrict__ x,
    const float* __restrict__ W_ih0, const float* __restrict__ W_hh0,
    const float* __restrict__ b_ih0, const float* __restrict__ b_hh0,
    const float* __restrict__ W_ih1, const float* __restrict__ W_hh1,
    const float* __restrict__ b_ih1, const float* __restrict__ b_hh1,
    const float* __restrict__ W_fc,  const float* __restrict__ b_fc,
    float* __restrict__ out)
{
    const int b    = blockIdx.x;
    const int tid  = threadIdx.x;
    const int wid  = tid >> 6;
    const int lane = tid & 63;
    const int o    = lane & 7;
    const int kg   = lane >> 3;

    __shared__ float h0r[16][NH];   // A -> B ring
    __shared__ float pir[16][NH];   // B -> C ring
    __shared__ float h1r[16][NH];   // C -> D ring
    __shared__ float ur[32][NH];    // D -> A ring (u = Wih0@x + bias0)
    __shared__ int   fa, fb, fc, fd, fu;

    if (tid == 0) { fa = -1; fb = -1; fc = -1; fd = -1; fu = -1; }
    __syncthreads();

    volatile int* vfa = &fa;
    volatile int* vfb = &fb;
    volatile int* vfc = &fc;
    volatile int* vfd = &fd;
    volatile int* vfu = &fu;

    const float*  xb   = x   + (size_t)b * NT * NI;
    float*        outb = out + (size_t)b * NT * NO;
    const size_t  hid  = (size_t)NB * NT * NO;

    if (wid == 0) {
        // ================= wave A: layer-0 chain (VALU gather) =================
        float w[NH];
        #pragma unroll
        for (int k = 0; k < NH; ++k) w[k] = W_hh0[lane * NH + k];
        float h0n = 0.0f;

        for (int t = 0; t < NT; ++t) {
            if ((t & 7) == 0) {
                const int needU = (t + 7 < NT) ? t + 7 : NT - 1;
                while (*vfu < needU) {}            // u availability (D ~13 ahead)
                while (*vfb < t - 9) {}            // h0r slot reuse vs B
                asm volatile("" ::: "memory");
            }
            const float uv = ur[t & 31][lane];     // ds_read; hidden under dot

            float c0 = 0.f, c1 = 0.f, c2 = 0.f, c3 = 0.f;
            #pragma unroll
            for (int k = 0; k < NH; k += 8) {
                const float s0 = rlane(h0n, k + 0), s1 = rlane(h0n, k + 1);
                const float s2 = rlane(h0n, k + 2), s3 = rlane(h0n, k + 3);
                const float s4 = rlane(h0n, k + 4), s5 = rlane(h0n, k + 5);
                const float s6 = rlane(h0n, k + 6), s7 = rlane(h0n, k + 7);
                c0 = fmaf(s0, w[k + 0], c0); c1 = fmaf(s1, w[k + 1], c1);
                c2 = fmaf(s2, w[k + 2], c2); c3 = fmaf(s3, w[k + 3], c3);
                c0 = fmaf(s4, w[k + 4], c0); c1 = fmaf(s5, w[k + 5], c1);
                c2 = fmaf(s6, w[k + 6], c2); c3 = fmaf(s7, w[k + 7], c3);
            }
            h0n = tanh_fast(((c0 + c1) + (c2 + c3)) + uv);

            h0r[t & 15][lane] = h0n;
            asm volatile("s_waitcnt lgkmcnt(0)" ::: "memory");
            *vfa = t;                              // publish every step
        }
        out[hid + (size_t)b * NH + lane] = h0n;                     // h0 final
    } else if (wid == 1) {
        // ================= wave B: pi producer (LDS gather) =================
        v2f w2[NH / 2];
        #pragma unroll
        for (int k = 0; k < NH / 2; ++k)
            w2[k] = v2f{W_ih1[lane * NH + 2 * k], W_ih1[lane * NH + 2 * k + 1]};

        for (int t = 0; t < NT; ++t) {
            while (*vfa < t) {}                    // h0[t] available
            if ((t & 7) == 0) {
                while (*vfc < t - 9) {}            // pir slot reuse vs C
            }
            asm volatile("" ::: "memory");

            const float4* hp = (const float4*)(&h0r[t & 15][0]);
            v2f a0 = {0.f, 0.f}, a1 = {0.f, 0.f}, a2 = {0.f, 0.f}, a3 = {0.f, 0.f};
            #pragma unroll
            for (int k = 0; k < 16; ++k) {
                const float4 g = hp[k];
                const v2f lo = {g.x, g.y}, hi = {g.z, g.w};
                if (k & 1) { a2 = fma2(lo, w2[2 * k], a2); a3 = fma2(hi, w2[2 * k + 1], a3); }
                else       { a0 = fma2(lo, w2[2 * k], a0); a1 = fma2(hi, w2[2 * k + 1], a1); }
            }
            const v2f sv = (a0 + a1) + (a2 + a3);
            pir[t & 15][lane] = sv.x + sv.y;
            asm volatile("s_waitcnt lgkmcnt(0)" ::: "memory");
            *vfb = t;                              // publish every step
        }
    } else if (wid == 2) {
        // ================= wave C: layer-1 chain (VALU gather) =================
        float w[NH];
        #pragma unroll
        for (int k = 0; k < NH; ++k) w[k] = W_hh1[lane * NH + k];
        const float bias1 = b_ih1[lane] + b_hh1[lane];
        float h1n = 0.0f;

        for (int t = 0; t < NT; ++t) {
            while (*vfb < t) {}                    // pi[t] available
            if ((t & 7) == 0) {
                while (*vfd < t - 9) {}            // h1r slot reuse vs D
            }
            asm volatile("" ::: "memory");
            const float pv = pir[t & 15][lane];    // ds_read; hidden under dot

            float c0 = bias1, c1 = 0.f, c2 = 0.f, c3 = 0.f;
            #pragma unroll
            for (int k = 0; k < NH; k += 8) {
                const float s0 = rlane(h1n, k + 0), s1 = rlane(h1n, k + 1);
                const float s2 = rlane(h1n, k + 2), s3 = rlane(h1n, k + 3);
                const float s4 = rlane(h1n, k + 4), s5 = rlane(h1n, k + 5);
                const float s6 = rlane(h1n, k + 6), s7 = rlane(h1n, k + 7);
                c0 = fmaf(s0, w[k + 0], c0); c1 = fmaf(s1, w[k + 1], c1);
                c2 = fmaf(s2, w[k + 2], c2); c3 = fmaf(s3, w[k + 3], c3);
                c0 = fmaf(s4, w[k + 4], c0); c1 = fmaf(s5, w[k + 5], c1);
                c2 = fmaf(s6, w[k + 6], c2); c3 = fmaf(s7, w[k + 7], c3);
            }
            h1n = tanh_fast(((c0 + c1) + (c2 + c3)) + pv);

            h1r[t & 15][lane] = h1n;
            asm volatile("s_waitcnt lgkmcnt(0)" ::: "memory");
            *vfc = t;                              // publish every step
        }
        out[hid + (size_t)NB * NH + (size_t)b * NH + lane] = h1n;   // h1 final
    } else {
        // ================= wave D: u producer + FC + store =================
        float wih0r[NI];
        #pragma unroll
        for (int i = 0; i < NI; ++i) wih0r[i] = W_ih0[lane * NI + i];
        const float bias0 = b_ih0[lane] + b_hh0[lane];
        float wfcr[8];
        #pragma unroll
        for (int m = 0; m < 8; ++m) wfcr[m] = W_fc[o * NH + kg * 8 + m];
        const float bfc = b_fc[o];

        // prologue: u[0..15]
        for (int s = 0; s < 16; ++s) {
            const float4 xa = *(const float4*)(xb + (size_t)s * NI);
            const float4 xc = *(const float4*)(xb + (size_t)s * NI + 4);
            float u = bias0;
            u = fmaf(xa.x, wih0r[0], u); u = fmaf(xa.y, wih0r[1], u);
            u = fmaf(xa.z, wih0r[2], u); u = fmaf(xa.w, wih0r[3], u);
            u = fmaf(xc.x, wih0r[4], u); u = fmaf(xc.y, wih0r[5], u);
            u = fmaf(xc.z, wih0r[6], u); u = fmaf(xc.w, wih0r[7], u);
            ur[s][lane] = u;
        }
        asm volatile("s_waitcnt lgkmcnt(0)" ::: "memory");
        *vfu = 15;

        // x register pipeline: px holds x[t+16]
        float4 px0 = {0,0,0,0}, px1 = {0,0,0,0};
        if (16 < NT) {
            px0 = *(const float4*)(xb + (size_t)16 * NI);
            px1 = *(const float4*)(xb + (size_t)16 * NI + 4);
        }

        for (int t = 0; t < NT; ++t) {
            const int tp = t + 16;
            if (tp < NT) {
                float u = bias0;
                u = fmaf(px0.x, wih0r[0], u); u = fmaf(px0.y, wih0r[1], u);
                u = fmaf(px0.z, wih0r[2], u); u = fmaf(px0.w, wih0r[3], u);
                u = fmaf(px1.x, wih0r[4], u); u = fmaf(px1.y, wih0r[5], u);
                u = fmaf(px1.z, wih0r[6], u); u = fmaf(px1.w, wih0r[7], u);
                ur[tp & 31][lane] = u;
                if (tp + 1 < NT) {                 // issue next x load (1 ahead)
                    px0 = *(const float4*)(xb + (size_t)(tp + 1) * NI);
                    px1 = *(const float4*)(xb + (size_t)(tp + 1) * NI + 4);
                }
            }
            if ((t & 3) == 3) {                    // publish u progress
                asm volatile("s_waitcnt lgkmcnt(0)" ::: "memory");
                *vfu = (tp < NT) ? tp : NT - 1;
            }

            while (*vfc < t) {}                    // h1[t] available
            asm volatile("" ::: "memory");
            const float4 u0 = *(const float4*)(&h1r[t & 15][kg * 8]);
            const float4 u1 = *(const float4*)(&h1r[t & 15][kg * 8 + 4]);
            float p = u0.x * wfcr[0] + u0.y * wfcr[1] + u0.z * wfcr[2] + u0.w * wfcr[3]
                    + u1.x * wfcr[4] + u1.y * wfcr[5] + u1.z * wfcr[6] + u1.w * wfcr[7];
            p += __shfl_xor(p, 8);
            p += __shfl_xor(p, 16);
            p += __shfl_xor(p, 32);
            if (lane < NO) outb[(size_t)t * NO + o] = p + bfc;   // fire-and-forget

            if ((t & 3) == 3) {                    // h1r consumption progress
                asm volatile("s_waitcnt lgkmcnt(0)" ::: "memory");
                *vfd = t;
            }
        }
    }
}

extern "C" void kernel_launch(void* const* d_in, const int* in_sizes, int n_in,
                              void* d_out, int out_size, void* d_ws, size_t ws_size,
                              hipStream_t stream) {
    const float* x     = (const float*)d_in[0];
    const float* W_ih0 = (const float*)d_in[1];
    const float* W_hh0 = (const float*)d_in[2];
    const float* b_ih0 = (const float*)d_in[3];
    const float* b_hh0 = (const float*)d_in[4];
    const float* W_ih1 = (const float*)d_in[5];
    const float* W_hh1 = (const float*)d_in[6];
    const float* b_ih1 = (const float*)d_in[7];
    const float* b_hh1 = (const float*)d_in[8];
    const float* W_fc  = (const float*)d_in[9];
    const float* b_fc  = (const float*)d_in[10];

    rnn_quad<<<dim3(NB), dim3(256), 0, stream>>>(
        x, W_ih0, W_hh0, b_ih0, b_hh0,
        W_ih1, W_hh1, b_ih1, b_hh1, W_fc, b_fc,
        (float*)d_out);
}